// Round 1
// baseline (359.259 us; speedup 1.0000x reference)
//
#include <hip/hip_runtime.h>

typedef __attribute__((ext_vector_type(8))) _Float16 half8;
typedef __attribute__((ext_vector_type(4))) float f32x4;

#define MFMA16(a, b, c) __builtin_amdgcn_mfma_f32_16x16x32_f16((a), (b), (c), 0, 0, 0)

// B=8, L=128, N=64, D=256, H=8, dk=32.  Tokens in (b,l,n) order, M = 65536.

// ---------------- weight fp32 -> fp16 conversion ----------------
__global__ __launch_bounds__(256) void cvt_weights(
    const float* __restrict__ w0, const float* __restrict__ w1,
    const float* __restrict__ w2, const float* __restrict__ w3,
    const float* __restrict__ w4, const float* __restrict__ w5,
    const float* __restrict__ w6, const float* __restrict__ w7,
    _Float16* __restrict__ out)
{
    const float* src[8] = {w0, w1, w2, w3, w4, w5, w6, w7};
    const int m = blockIdx.y;
    const int i = blockIdx.x * 256 + threadIdx.x;
    out[(size_t)m * 65536 + i] = (_Float16)src[m][i];
}

// ---------------- GEMM: C[M,256] = A[M,256] @ W[256,256]^T (+bias) ----------------
// W is torch-Linear layout [out,in] row-major -> rows of W are exactly the
// MFMA B-operand fragments (col = out-row, K contiguous).  128x128 tile, BK=64,
// 4 waves (2x2), each wave 64x64 = 4x4 16x16x32 tiles.
template <bool A_F32, bool ADD_BIAS, bool OUT_F32>
__global__ __launch_bounds__(256) void gemm_k256(
    const void* __restrict__ Ap, const _Float16* __restrict__ W,
    const float* __restrict__ bias, void* __restrict__ Cp)
{
    __shared__ __align__(16) _Float16 As[128][72];  // +8 pad: 144B rows
    __shared__ __align__(16) _Float16 Bs[128][72];

    const int tid  = threadIdx.x;
    const int lane = tid & 63;
    const int l15  = lane & 15;
    const int lhi  = lane >> 4;
    const int wid  = tid >> 6;
    const int m0   = blockIdx.x * 128;
    const int n0   = blockIdx.y * 128;
    const int wr   = (wid >> 1) * 64;
    const int wc   = (wid & 1) * 64;

    f32x4 acc[4][4] = {};

    for (int kt = 0; kt < 4; ++kt) {
        const int k0 = kt * 64;
        // stage B (weights, already fp16) and A (fp32->fp16 or fp16 copy)
#pragma unroll
        for (int i = 0; i < 4; ++i) {
            const int slot = i * 256 + tid;    // 1024 slots of 8 elems
            const int r = slot >> 3;
            const int c = (slot & 7) * 8;
            *(half8*)(&Bs[r][c]) =
                *(const half8*)(W + (size_t)(n0 + r) * 256 + k0 + c);
            if (A_F32) {
                const float* A = (const float*)Ap;
                const float* srcp = A + (size_t)(m0 + r) * 256 + k0 + c;
                f32x4 a0 = *(const f32x4*)(srcp);
                f32x4 a1 = *(const f32x4*)(srcp + 4);
                half8 hv;
#pragma unroll
                for (int jj = 0; jj < 4; ++jj) {
                    hv[jj]     = (_Float16)a0[jj];
                    hv[4 + jj] = (_Float16)a1[jj];
                }
                *(half8*)(&As[r][c]) = hv;
            } else {
                const _Float16* A = (const _Float16*)Ap;
                *(half8*)(&As[r][c]) =
                    *(const half8*)(A + (size_t)(m0 + r) * 256 + k0 + c);
            }
        }
        __syncthreads();
#pragma unroll
        for (int kk = 0; kk < 2; ++kk) {
            half8 af[4], bfr[4];
#pragma unroll
            for (int mi = 0; mi < 4; ++mi)
                af[mi] = *(const half8*)(&As[wr + mi * 16 + l15][kk * 32 + lhi * 8]);
#pragma unroll
            for (int nj = 0; nj < 4; ++nj)
                bfr[nj] = *(const half8*)(&Bs[wc + nj * 16 + l15][kk * 32 + lhi * 8]);
#pragma unroll
            for (int mi = 0; mi < 4; ++mi)
#pragma unroll
                for (int nj = 0; nj < 4; ++nj)
                    acc[mi][nj] = MFMA16(af[mi], bfr[nj], acc[mi][nj]);
        }
        __syncthreads();
    }

    // epilogue: D layout col = lane&15, row = (lane>>4)*4 + j
#pragma unroll
    for (int mi = 0; mi < 4; ++mi) {
#pragma unroll
        for (int nj = 0; nj < 4; ++nj) {
            const int col = n0 + wc + nj * 16 + l15;
            const float bv = ADD_BIAS ? bias[col] : 0.0f;
            const int row = m0 + wr + mi * 16 + lhi * 4;
#pragma unroll
            for (int j = 0; j < 4; ++j) {
                const float val = acc[mi][nj][j] + bv;
                if (OUT_F32)
                    ((float*)Cp)[(size_t)(row + j) * 256 + col] = val;
                else
                    ((_Float16*)Cp)[(size_t)(row + j) * 256 + col] = (_Float16)val;
            }
        }
    }
}

// ---------------- temporal attention: per (b,n,h), seq = L = 128 ----------------
// 4 waves, each owns 32 query rows.  Q/K fragments straight from global.
__global__ __launch_bounds__(256) void attn_temporal(
    const _Float16* __restrict__ Q, const _Float16* __restrict__ K,
    const _Float16* __restrict__ V, _Float16* __restrict__ O)
{
    __shared__ __align__(16) _Float16 Vt[32][136];   // V^T: [d][l], 272B rows
    __shared__ __align__(16) _Float16 P[128][136];   // probabilities

    const int tid  = threadIdx.x;
    const int lane = tid & 63;
    const int l15  = lane & 15;
    const int lhi  = lane >> 4;
    const int wid  = tid >> 6;
    const int bidx = blockIdx.x;
    const int h = bidx & 7;
    const int n = (bidx >> 3) & 63;
    const int b = bidx >> 9;
    const size_t LSTRIDE = 64 * 256;                 // token stride per l
    const size_t base = (((size_t)b * 128) * 64 + n) * 256 + (size_t)h * 32;

    // cooperative V transpose into LDS
    {
        const int l  = tid >> 1;
        const int dh = (tid & 1) * 16;
        const _Float16* srcp = V + base + (size_t)l * LSTRIDE + dh;
        half8 v0 = *(const half8*)(srcp);
        half8 v1 = *(const half8*)(srcp + 8);
#pragma unroll
        for (int j = 0; j < 8; ++j) {
            Vt[dh + j][l]     = v0[j];
            Vt[dh + 8 + j][l] = v1[j];
        }
    }
    __syncthreads();

    // S = Q K^T  (dk = 32 = one MFMA K-step)
    half8 qa[2];
#pragma unroll
    for (int mi = 0; mi < 2; ++mi)
        qa[mi] = *(const half8*)(Q + base +
                  (size_t)(wid * 32 + mi * 16 + l15) * LSTRIDE + lhi * 8);
    f32x4 s[2][8] = {};
#pragma unroll
    for (int nt = 0; nt < 8; ++nt) {
        half8 kb = *(const half8*)(K + base +
                    (size_t)(nt * 16 + l15) * LSTRIDE + lhi * 8);
#pragma unroll
        for (int mi = 0; mi < 2; ++mi)
            s[mi][nt] = MFMA16(qa[mi], kb, s[mi][nt]);
    }

    // softmax per row (row = wid*32 + mi*16 + lhi*4 + j, cols spread over
    // 16 lanes x 8 tiles); scale folded into exp argument.
    const float scale = 0.17677669529663687f;  // 1/sqrt(32)
#pragma unroll
    for (int mi = 0; mi < 2; ++mi) {
#pragma unroll
        for (int j = 0; j < 4; ++j) {
            float m = s[mi][0][j];
#pragma unroll
            for (int nt = 1; nt < 8; ++nt) m = fmaxf(m, s[mi][nt][j]);
            m = fmaxf(m, __shfl_xor(m, 1));
            m = fmaxf(m, __shfl_xor(m, 2));
            m = fmaxf(m, __shfl_xor(m, 4));
            m = fmaxf(m, __shfl_xor(m, 8));
            float sum = 0.0f;
#pragma unroll
            for (int nt = 0; nt < 8; ++nt) {
                const float p = __expf((s[mi][nt][j] - m) * scale);
                s[mi][nt][j] = p;
                sum += p;
            }
            sum += __shfl_xor(sum, 1);
            sum += __shfl_xor(sum, 2);
            sum += __shfl_xor(sum, 4);
            sum += __shfl_xor(sum, 8);
            const float inv = 1.0f / sum;
            const int prow = wid * 32 + mi * 16 + lhi * 4 + j;
#pragma unroll
            for (int nt = 0; nt < 8; ++nt)
                P[prow][nt * 16 + l15] = (_Float16)(s[mi][nt][j] * inv);
        }
    }
    __syncthreads();

    // O = P V
    f32x4 o[2][2] = {};
#pragma unroll
    for (int ks = 0; ks < 4; ++ks) {
        half8 pa[2];
#pragma unroll
        for (int mi = 0; mi < 2; ++mi)
            pa[mi] = *(const half8*)(&P[wid * 32 + mi * 16 + l15][ks * 32 + lhi * 8]);
#pragma unroll
        for (int dt = 0; dt < 2; ++dt) {
            half8 vb = *(const half8*)(&Vt[dt * 16 + l15][ks * 32 + lhi * 8]);
#pragma unroll
            for (int mi = 0; mi < 2; ++mi)
                o[mi][dt] = MFMA16(pa[mi], vb, o[mi][dt]);
        }
    }
#pragma unroll
    for (int mi = 0; mi < 2; ++mi)
#pragma unroll
        for (int dt = 0; dt < 2; ++dt)
#pragma unroll
            for (int j = 0; j < 4; ++j)
                O[base + (size_t)(wid * 32 + mi * 16 + lhi * 4 + j) * LSTRIDE +
                  dt * 16 + l15] = (_Float16)o[mi][dt][j];
}

// ---------------- social attention: per (b,l,h), seq = N = 64 ----------------
// 4 waves, each owns 16 query rows.
__global__ __launch_bounds__(256) void attn_social(
    const _Float16* __restrict__ Q, const _Float16* __restrict__ K,
    const _Float16* __restrict__ V, _Float16* __restrict__ O)
{
    __shared__ __align__(16) _Float16 Vt[32][72];
    __shared__ __align__(16) _Float16 P[64][72];

    const int tid  = threadIdx.x;
    const int lane = tid & 63;
    const int l15  = lane & 15;
    const int lhi  = lane >> 4;
    const int wid  = tid >> 6;
    const int bidx = blockIdx.x;
    const int h = bidx & 7;
    const int l = (bidx >> 3) & 127;
    const int b = bidx >> 10;
    const size_t base = (((size_t)b * 128 + l) * 64) * 256 + (size_t)h * 32;

    {
        const int n  = tid >> 2;
        const int dq = (tid & 3) * 8;
        half8 v0 = *(const half8*)(V + base + (size_t)n * 256 + dq);
#pragma unroll
        for (int j = 0; j < 8; ++j) Vt[dq + j][n] = v0[j];
    }
    __syncthreads();

    half8 qa = *(const half8*)(Q + base + (size_t)(wid * 16 + l15) * 256 + lhi * 8);
    f32x4 s[4] = {};
#pragma unroll
    for (int nt = 0; nt < 4; ++nt) {
        half8 kb = *(const half8*)(K + base + (size_t)(nt * 16 + l15) * 256 + lhi * 8);
        s[nt] = MFMA16(qa, kb, s[nt]);
    }

    const float scale = 0.17677669529663687f;
#pragma unroll
    for (int j = 0; j < 4; ++j) {
        float m = s[0][j];
#pragma unroll
        for (int nt = 1; nt < 4; ++nt) m = fmaxf(m, s[nt][j]);
        m = fmaxf(m, __shfl_xor(m, 1));
        m = fmaxf(m, __shfl_xor(m, 2));
        m = fmaxf(m, __shfl_xor(m, 4));
        m = fmaxf(m, __shfl_xor(m, 8));
        float sum = 0.0f;
#pragma unroll
        for (int nt = 0; nt < 4; ++nt) {
            const float p = __expf((s[nt][j] - m) * scale);
            s[nt][j] = p;
            sum += p;
        }
        sum += __shfl_xor(sum, 1);
        sum += __shfl_xor(sum, 2);
        sum += __shfl_xor(sum, 4);
        sum += __shfl_xor(sum, 8);
        const float inv = 1.0f / sum;
        const int prow = wid * 16 + lhi * 4 + j;
#pragma unroll
        for (int nt = 0; nt < 4; ++nt)
            P[prow][nt * 16 + l15] = (_Float16)(s[nt][j] * inv);
    }
    __syncthreads();

    f32x4 o[2] = {};
#pragma unroll
    for (int ks = 0; ks < 2; ++ks) {
        half8 pa = *(const half8*)(&P[wid * 16 + l15][ks * 32 + lhi * 8]);
#pragma unroll
        for (int dt = 0; dt < 2; ++dt) {
            half8 vb = *(const half8*)(&Vt[dt * 16 + l15][ks * 32 + lhi * 8]);
            o[dt] = MFMA16(pa, vb, o[dt]);
        }
    }
#pragma unroll
    for (int dt = 0; dt < 2; ++dt)
#pragma unroll
        for (int j = 0; j < 4; ++j)
            O[base + (size_t)(wid * 16 + lhi * 4 + j) * 256 + dt * 16 + l15] =
                (_Float16)o[dt][j];
}

// ---------------- host launch ----------------
extern "C" void kernel_launch(void* const* d_in, const int* in_sizes, int n_in,
                              void* d_out, int out_size, void* d_ws, size_t ws_size,
                              hipStream_t stream)
{
    const float* q    = (const float*)d_in[0];
    const float* k    = (const float*)d_in[1];
    const float* v    = (const float*)d_in[2];
    const float* t_wq = (const float*)d_in[3];
    const float* t_wk = (const float*)d_in[4];
    const float* t_wv = (const float*)d_in[5];
    const float* t_wd = (const float*)d_in[6];
    const float* t_bd = (const float*)d_in[7];
    const float* s_wq = (const float*)d_in[8];
    const float* s_wk = (const float*)d_in[9];
    const float* s_wv = (const float*)d_in[10];
    const float* s_wd = (const float*)d_in[11];
    const float* s_bd = (const float*)d_in[12];

    // workspace layout (fp16): 8 weights (1 MB) + 6 token-order slots (32 MB each)
    _Float16* Wb = (_Float16*)d_ws;
    const size_t SLOT = (size_t)65536 * 256;
    _Float16* slots = Wb + 8 * 65536;
    _Float16* Qt = slots;
    _Float16* Kt = slots + SLOT;
    _Float16* Vt = slots + 2 * SLOT;
    _Float16* Ks = slots + 3 * SLOT;
    _Float16* Vs = slots + 4 * SLOT;
    _Float16* Ot = slots + 5 * SLOT;
    _Float16* Tout = Qt;  // dead after temporal attention
    _Float16* Qs   = Kt;  // dead after temporal attention
    _Float16* Os   = Vt;  // dead after temporal attention

    cvt_weights<<<dim3(256, 8), 256, 0, stream>>>(
        t_wq, t_wk, t_wv, t_wd, s_wq, s_wk, s_wv, s_wd, Wb);

    const dim3 gg(512, 2), gb(256);
    // stage-1 projections (A = fp32 inputs)
    gemm_k256<true, false, false><<<gg, gb, 0, stream>>>(q, Wb + 0 * 65536, nullptr, Qt);
    gemm_k256<true, false, false><<<gg, gb, 0, stream>>>(k, Wb + 1 * 65536, nullptr, Kt);
    gemm_k256<true, false, false><<<gg, gb, 0, stream>>>(v, Wb + 2 * 65536, nullptr, Vt);
    gemm_k256<true, false, false><<<gg, gb, 0, stream>>>(k, Wb + 5 * 65536, nullptr, Ks);
    gemm_k256<true, false, false><<<gg, gb, 0, stream>>>(v, Wb + 6 * 65536, nullptr, Vs);

    attn_temporal<<<4096, 256, 0, stream>>>(Qt, Kt, Vt, Ot);

    // t_out = Ot @ t_wd^T + t_bd ; Qs = t_out @ s_wq^T
    gemm_k256<false, true, false><<<gg, gb, 0, stream>>>(Ot, Wb + 3 * 65536, t_bd, Tout);
    gemm_k256<false, false, false><<<gg, gb, 0, stream>>>(Tout, Wb + 4 * 65536, nullptr, Qs);

    attn_social<<<8192, 256, 0, stream>>>(Qs, Ks, Vs, Os);

    gemm_k256<false, true, true><<<gg, gb, 0, stream>>>(Os, Wb + 7 * 65536, s_bd, (float*)d_out);

    (void)in_sizes; (void)n_in; (void)out_size; (void)ws_size;
}

// Round 2
// 334.862 us; speedup vs baseline: 1.0729x; 1.0729x over previous
//
#include <hip/hip_runtime.h>

typedef __attribute__((ext_vector_type(8))) _Float16 half8;
typedef __attribute__((ext_vector_type(4))) float f32x4;

#define MFMA16(a, b, c) __builtin_amdgcn_mfma_f32_16x16x32_f16((a), (b), (c), 0, 0, 0)

// B=8, L=128, N=64, D=256, H=8, dk=32.  M = 65536 tokens.
// Token orders: LN = (b,l,n) [input/social order], NL = (b,n,l) [temporal order].

__device__ inline int map_ln_nl(int t) {   // (b,l,n) -> (b,n,l)
    return (t & ~8191) | ((t & 63) << 7) | ((t >> 6) & 127);
}
__device__ inline int map_nl_ln(int t) {   // (b,n,l) -> (b,l,n)
    return (t & ~8191) | ((t & 127) << 6) | ((t >> 7) & 63);
}

// ---------------- weight fp32 -> fp16 conversion ----------------
// slots: 0=t_wq 1=t_wk 2=s_wk 3=t_wv 4=s_wv 5=W2(made elsewhere) 6=s_wd
__global__ __launch_bounds__(256) void cvt_weights(
    const float* __restrict__ w0, const float* __restrict__ w1,
    const float* __restrict__ w2, const float* __restrict__ w3,
    const float* __restrict__ w4, const float* __restrict__ w5,
    _Float16* __restrict__ out)
{
    const float* src[6] = {w0, w1, w2, w3, w4, w5};
    const int m = blockIdx.y;
    const int slot = (m < 5) ? m : 6;
    const int i = blockIdx.x * 256 + threadIdx.x;
    out[(size_t)slot * 65536 + i] = (_Float16)src[m][i];
}

// ---------------- W2 = s_wq @ t_wd  (fp32 accum), b2 = s_wq @ t_bd ----------------
__global__ __launch_bounds__(256) void make_w2(
    const float* __restrict__ s_wq, const float* __restrict__ t_wd,
    const float* __restrict__ t_bd, _Float16* __restrict__ W2,
    float* __restrict__ b2)
{
    const int e = blockIdx.x;
    const int d = threadIdx.x;
    float acc = 0.0f;
    for (int c = 0; c < 256; ++c)
        acc = fmaf(s_wq[e * 256 + c], t_wd[c * 256 + d], acc);
    W2[e * 256 + d] = (_Float16)acc;
    if (d == 0) {
        float bb = 0.0f;
        for (int c = 0; c < 256; ++c) bb = fmaf(s_wq[e * 256 + c], t_bd[c], bb);
        b2[e] = bb;
    }
}

// ---------------- GEMM: C[M,Ncols] = A[M,256] @ W[Ncols,256]^T (+bias) ----------------
// 128x128 tile, BK=64, 4 waves (2x2), each wave 64x64 = 4x4 16x16x32 tiles.
// ROWMAP: 0 ident, 1 LN->NL, 2 NL->LN.  DUAL: coltiles 0-1 -> C0 (LN->NL),
// coltiles 2-3 -> C1 (ident, col-256).
template <bool A_F32, int ROWMAP, bool DUAL, bool ADD_BIAS, bool OUT_F32>
__global__ __launch_bounds__(256) void gemm_k256(
    const void* __restrict__ Ap, const _Float16* __restrict__ W,
    const float* __restrict__ bias, void* __restrict__ C0, void* __restrict__ C1)
{
    __shared__ __align__(16) _Float16 As[128][72];  // +8 pad: 144B rows
    __shared__ __align__(16) _Float16 Bs[128][72];

    const int tid  = threadIdx.x;
    const int lane = tid & 63;
    const int l15  = lane & 15;
    const int lhi  = lane >> 4;
    const int wid  = tid >> 6;
    const int m0   = blockIdx.x * 128;
    const int n0   = blockIdx.y * 128;
    const int wr   = (wid >> 1) * 64;
    const int wc   = (wid & 1) * 64;

    f32x4 acc[4][4] = {};

    for (int kt = 0; kt < 4; ++kt) {
        const int k0 = kt * 64;
#pragma unroll
        for (int i = 0; i < 4; ++i) {
            const int slot = i * 256 + tid;    // 1024 slots of 8 elems
            const int r = slot >> 3;
            const int c = (slot & 7) * 8;
            *(half8*)(&Bs[r][c]) =
                *(const half8*)(W + (size_t)(n0 + r) * 256 + k0 + c);
            if (A_F32) {
                const float* A = (const float*)Ap;
                const float* srcp = A + (size_t)(m0 + r) * 256 + k0 + c;
                f32x4 a0 = *(const f32x4*)(srcp);
                f32x4 a1 = *(const f32x4*)(srcp + 4);
                half8 hv;
#pragma unroll
                for (int jj = 0; jj < 4; ++jj) {
                    hv[jj]     = (_Float16)a0[jj];
                    hv[4 + jj] = (_Float16)a1[jj];
                }
                *(half8*)(&As[r][c]) = hv;
            } else {
                const _Float16* A = (const _Float16*)Ap;
                *(half8*)(&As[r][c]) =
                    *(const half8*)(A + (size_t)(m0 + r) * 256 + k0 + c);
            }
        }
        __syncthreads();
#pragma unroll
        for (int kk = 0; kk < 2; ++kk) {
            half8 af[4], bfr[4];
#pragma unroll
            for (int mi = 0; mi < 4; ++mi)
                af[mi] = *(const half8*)(&As[wr + mi * 16 + l15][kk * 32 + lhi * 8]);
#pragma unroll
            for (int nj = 0; nj < 4; ++nj)
                bfr[nj] = *(const half8*)(&Bs[wc + nj * 16 + l15][kk * 32 + lhi * 8]);
#pragma unroll
            for (int mi = 0; mi < 4; ++mi)
#pragma unroll
                for (int nj = 0; nj < 4; ++nj)
                    acc[mi][nj] = MFMA16(af[mi], bfr[nj], acc[mi][nj]);
        }
        __syncthreads();
    }

    // epilogue: D layout col = lane&15, row = (lane>>4)*4 + j
    const bool hi = DUAL && (blockIdx.y >= 2);
    void* Cp = hi ? C1 : C0;
    const int cadj = hi ? 256 : 0;
#pragma unroll
    for (int mi = 0; mi < 4; ++mi) {
#pragma unroll
        for (int nj = 0; nj < 4; ++nj) {
            const int col = n0 + wc + nj * 16 + l15 - cadj;
            const float bv = ADD_BIAS ? bias[col] : 0.0f;
#pragma unroll
            for (int j = 0; j < 4; ++j) {
                const int trow = m0 + wr + mi * 16 + lhi * 4 + j;
                int orow;
                if (DUAL)            orow = hi ? trow : map_ln_nl(trow);
                else if (ROWMAP == 1) orow = map_ln_nl(trow);
                else if (ROWMAP == 2) orow = map_nl_ln(trow);
                else                  orow = trow;
                const float val = acc[mi][nj][j] + bv;
                if (OUT_F32)
                    ((float*)Cp)[(size_t)orow * 256 + col] = val;
                else
                    ((_Float16*)Cp)[(size_t)orow * 256 + col] = (_Float16)val;
            }
        }
    }
}

// ---------------- temporal attention: per (b,n,h), seq = L = 128 ----------------
// All tensors in NL layout (b,n,l,d): sequence rows are 512B apart (contiguous-ish).
__global__ __launch_bounds__(256) void attn_temporal(
    const _Float16* __restrict__ Q, const _Float16* __restrict__ K,
    const _Float16* __restrict__ V, _Float16* __restrict__ O)
{
    __shared__ __align__(16) _Float16 Vt[32][136];   // V^T: [d][l]
    __shared__ __align__(16) _Float16 P[128][136];   // probabilities

    const int tid  = threadIdx.x;
    const int lane = tid & 63;
    const int l15  = lane & 15;
    const int lhi  = lane >> 4;
    const int wid  = tid >> 6;
    const int bidx = blockIdx.x;
    const int h = bidx & 7;
    const int n = (bidx >> 3) & 63;
    const int b = bidx >> 9;
    const size_t base = ((size_t)(b * 64 + n) * 128) * 256 + (size_t)h * 32;

    // cooperative V transpose into LDS
    {
        const int l  = tid >> 1;
        const int dh = (tid & 1) * 16;
        const _Float16* srcp = V + base + (size_t)l * 256 + dh;
        half8 v0 = *(const half8*)(srcp);
        half8 v1 = *(const half8*)(srcp + 8);
#pragma unroll
        for (int j = 0; j < 8; ++j) {
            Vt[dh + j][l]     = v0[j];
            Vt[dh + 8 + j][l] = v1[j];
        }
    }
    __syncthreads();

    // S = Q K^T  (dk = 32 = one MFMA K-step)
    half8 qa[2];
#pragma unroll
    for (int mi = 0; mi < 2; ++mi)
        qa[mi] = *(const half8*)(Q + base +
                  (size_t)(wid * 32 + mi * 16 + l15) * 256 + lhi * 8);
    f32x4 s[2][8] = {};
#pragma unroll
    for (int nt = 0; nt < 8; ++nt) {
        half8 kb = *(const half8*)(K + base +
                    (size_t)(nt * 16 + l15) * 256 + lhi * 8);
#pragma unroll
        for (int mi = 0; mi < 2; ++mi)
            s[mi][nt] = MFMA16(qa[mi], kb, s[mi][nt]);
    }

    const float scale = 0.17677669529663687f;  // 1/sqrt(32)
#pragma unroll
    for (int mi = 0; mi < 2; ++mi) {
#pragma unroll
        for (int j = 0; j < 4; ++j) {
            float m = s[mi][0][j];
#pragma unroll
            for (int nt = 1; nt < 8; ++nt) m = fmaxf(m, s[mi][nt][j]);
            m = fmaxf(m, __shfl_xor(m, 1));
            m = fmaxf(m, __shfl_xor(m, 2));
            m = fmaxf(m, __shfl_xor(m, 4));
            m = fmaxf(m, __shfl_xor(m, 8));
            float sum = 0.0f;
#pragma unroll
            for (int nt = 0; nt < 8; ++nt) {
                const float p = __expf((s[mi][nt][j] - m) * scale);
                s[mi][nt][j] = p;
                sum += p;
            }
            sum += __shfl_xor(sum, 1);
            sum += __shfl_xor(sum, 2);
            sum += __shfl_xor(sum, 4);
            sum += __shfl_xor(sum, 8);
            const float inv = 1.0f / sum;
            const int prow = wid * 32 + mi * 16 + lhi * 4 + j;
#pragma unroll
            for (int nt = 0; nt < 8; ++nt)
                P[prow][nt * 16 + l15] = (_Float16)(s[mi][nt][j] * inv);
        }
    }
    __syncthreads();

    // O = P V
    f32x4 o[2][2] = {};
#pragma unroll
    for (int ks = 0; ks < 4; ++ks) {
        half8 pa[2];
#pragma unroll
        for (int mi = 0; mi < 2; ++mi)
            pa[mi] = *(const half8*)(&P[wid * 32 + mi * 16 + l15][ks * 32 + lhi * 8]);
#pragma unroll
        for (int dt = 0; dt < 2; ++dt) {
            half8 vb = *(const half8*)(&Vt[dt * 16 + l15][ks * 32 + lhi * 8]);
#pragma unroll
            for (int mi = 0; mi < 2; ++mi)
                o[mi][dt] = MFMA16(pa[mi], vb, o[mi][dt]);
        }
    }
#pragma unroll
    for (int mi = 0; mi < 2; ++mi)
#pragma unroll
        for (int dt = 0; dt < 2; ++dt)
#pragma unroll
            for (int j = 0; j < 4; ++j)
                O[base + (size_t)(wid * 32 + mi * 16 + lhi * 4 + j) * 256 +
                  dt * 16 + l15] = (_Float16)o[mi][dt][j];
}

// ---------------- social attention: per (b,l,h), seq = N = 64, LN layout ----------------
__global__ __launch_bounds__(256) void attn_social(
    const _Float16* __restrict__ Q, const _Float16* __restrict__ K,
    const _Float16* __restrict__ V, _Float16* __restrict__ O)
{
    __shared__ __align__(16) _Float16 Vt[32][72];
    __shared__ __align__(16) _Float16 P[64][72];

    const int tid  = threadIdx.x;
    const int lane = tid & 63;
    const int l15  = lane & 15;
    const int lhi  = lane >> 4;
    const int wid  = tid >> 6;
    const int bidx = blockIdx.x;
    const int h = bidx & 7;
    const int l = (bidx >> 3) & 127;
    const int b = bidx >> 10;
    const size_t base = (((size_t)b * 128 + l) * 64) * 256 + (size_t)h * 32;

    {
        const int n  = tid >> 2;
        const int dq = (tid & 3) * 8;
        half8 v0 = *(const half8*)(V + base + (size_t)n * 256 + dq);
#pragma unroll
        for (int j = 0; j < 8; ++j) Vt[dq + j][n] = v0[j];
    }
    __syncthreads();

    half8 qa = *(const half8*)(Q + base + (size_t)(wid * 16 + l15) * 256 + lhi * 8);
    f32x4 s[4] = {};
#pragma unroll
    for (int nt = 0; nt < 4; ++nt) {
        half8 kb = *(const half8*)(K + base + (size_t)(nt * 16 + l15) * 256 + lhi * 8);
        s[nt] = MFMA16(qa, kb, s[nt]);
    }

    const float scale = 0.17677669529663687f;
#pragma unroll
    for (int j = 0; j < 4; ++j) {
        float m = s[0][j];
#pragma unroll
        for (int nt = 1; nt < 4; ++nt) m = fmaxf(m, s[nt][j]);
        m = fmaxf(m, __shfl_xor(m, 1));
        m = fmaxf(m, __shfl_xor(m, 2));
        m = fmaxf(m, __shfl_xor(m, 4));
        m = fmaxf(m, __shfl_xor(m, 8));
        float sum = 0.0f;
#pragma unroll
        for (int nt = 0; nt < 4; ++nt) {
            const float p = __expf((s[nt][j] - m) * scale);
            s[nt][j] = p;
            sum += p;
        }
        sum += __shfl_xor(sum, 1);
        sum += __shfl_xor(sum, 2);
        sum += __shfl_xor(sum, 4);
        sum += __shfl_xor(sum, 8);
        const float inv = 1.0f / sum;
        const int prow = wid * 16 + lhi * 4 + j;
#pragma unroll
        for (int nt = 0; nt < 4; ++nt)
            P[prow][nt * 16 + l15] = (_Float16)(s[nt][j] * inv);
    }
    __syncthreads();

    f32x4 o[2] = {};
#pragma unroll
    for (int ks = 0; ks < 2; ++ks) {
        half8 pa = *(const half8*)(&P[wid * 16 + l15][ks * 32 + lhi * 8]);
#pragma unroll
        for (int dt = 0; dt < 2; ++dt) {
            half8 vb = *(const half8*)(&Vt[dt * 16 + l15][ks * 32 + lhi * 8]);
            o[dt] = MFMA16(pa, vb, o[dt]);
        }
    }
#pragma unroll
    for (int dt = 0; dt < 2; ++dt)
#pragma unroll
        for (int j = 0; j < 4; ++j)
            O[base + (size_t)(wid * 16 + lhi * 4 + j) * 256 + dt * 16 + l15] =
                (_Float16)o[dt][j];
}

// ---------------- host launch ----------------
extern "C" void kernel_launch(void* const* d_in, const int* in_sizes, int n_in,
                              void* d_out, int out_size, void* d_ws, size_t ws_size,
                              hipStream_t stream)
{
    const float* q    = (const float*)d_in[0];
    const float* k    = (const float*)d_in[1];
    const float* v    = (const float*)d_in[2];
    const float* t_wq = (const float*)d_in[3];
    const float* t_wk = (const float*)d_in[4];
    const float* t_wv = (const float*)d_in[5];
    const float* t_wd = (const float*)d_in[6];
    const float* t_bd = (const float*)d_in[7];
    const float* s_wq = (const float*)d_in[8];
    const float* s_wk = (const float*)d_in[9];
    const float* s_wv = (const float*)d_in[10];
    const float* s_wd = (const float*)d_in[11];
    const float* s_bd = (const float*)d_in[12];

    // workspace: 7 fp16 weight slots + b2 (fp32) + 6 activation slots (32 MB)
    _Float16* Wb = (_Float16*)d_ws;
    float* b2 = (float*)(Wb + 7 * 65536);
    const size_t SLOT = (size_t)65536 * 256;
    _Float16* slots = (_Float16*)(b2 + 256);
    _Float16* Qt = slots;             // NL
    _Float16* Kt = slots + SLOT;      // NL
    _Float16* Vt = slots + 2 * SLOT;  // NL
    _Float16* Ks = slots + 3 * SLOT;  // LN
    _Float16* Vs = slots + 4 * SLOT;  // LN
    _Float16* Ot = slots + 5 * SLOT;  // NL
    _Float16* Qs = Qt;                // LN (Qt dead after temporal attn)
    _Float16* Os = Kt;                // LN (Kt dead after temporal attn)

    cvt_weights<<<dim3(256, 6), 256, 0, stream>>>(
        t_wq, t_wk, s_wk, t_wv, s_wv, s_wd, Wb);
    make_w2<<<256, 256, 0, stream>>>(s_wq, t_wd, t_bd, Wb + 5 * 65536, b2);

    const dim3 gb(256);
    // stage-1 projections (A = fp32 inputs, LN rows)
    gemm_k256<true, 1, false, false, false><<<dim3(512, 2), gb, 0, stream>>>(
        q, Wb + 0 * 65536, nullptr, Qt, nullptr);
    gemm_k256<true, 1, true, false, false><<<dim3(512, 4), gb, 0, stream>>>(
        k, Wb + 1 * 65536, nullptr, Kt, Ks);
    gemm_k256<true, 1, true, false, false><<<dim3(512, 4), gb, 0, stream>>>(
        v, Wb + 3 * 65536, nullptr, Vt, Vs);

    attn_temporal<<<4096, 256, 0, stream>>>(Qt, Kt, Vt, Ot);

    // Qs = Ot @ W2^T + b2   (collapsed t_wd -> s_wq chain), NL rows -> LN out
    gemm_k256<false, 2, false, true, false><<<dim3(512, 2), gb, 0, stream>>>(
        Ot, Wb + 5 * 65536, b2, Qs, nullptr);

    attn_social<<<8192, 256, 0, stream>>>(Qs, Ks, Vs, Os);

    gemm_k256<false, 0, false, true, true><<<dim3(512, 2), gb, 0, stream>>>(
        Os, Wb + 6 * 65536, s_bd, d_out, nullptr);

    (void)in_sizes; (void)n_in; (void)out_size; (void)ws_size;
}

// Round 3
// 322.145 us; speedup vs baseline: 1.1152x; 1.0395x over previous
//
#include <hip/hip_runtime.h>

typedef __attribute__((ext_vector_type(8))) _Float16 half8;
typedef __attribute__((ext_vector_type(4))) float f32x4;

#define MFMA16(a, b, c) __builtin_amdgcn_mfma_f32_16x16x32_f16((a), (b), (c), 0, 0, 0)

// B=8, L=128, N=64, D=256, H=8, dk=32.  M = 65536 tokens.
// Token orders: LN = (b,l,n), NL = (b,n,l).

__device__ inline int map_ln_nl(int t) {   // (b,l,n) -> (b,n,l)
    return (t & ~8191) | ((t & 63) << 7) | ((t >> 6) & 127);
}
__device__ inline int map_nl_ln(int t) {   // (b,n,l) -> (b,l,n)
    return (t & ~8191) | ((t & 127) << 6) | ((t >> 7) & 63);
}

typedef const __attribute__((address_space(1))) unsigned int guint;
typedef __attribute__((address_space(3))) unsigned int luint;
__device__ inline void gld16(const _Float16* g, _Float16* l) {
    __builtin_amdgcn_global_load_lds((guint*)g, (luint*)l, 16, 0, 0);
}

// ---------------- weight fp32 -> fp16 ----------------
// slots: 0=t_wq 1=t_wk 2=s_wk 3=t_wv 4=s_wv 5=W2(made elsewhere) 6=s_wd
__global__ __launch_bounds__(256) void cvt_weights(
    const float* __restrict__ w0, const float* __restrict__ w1,
    const float* __restrict__ w2, const float* __restrict__ w3,
    const float* __restrict__ w4, const float* __restrict__ w5,
    _Float16* __restrict__ out)
{
    const float* src[6] = {w0, w1, w2, w3, w4, w5};
    const int m = blockIdx.y;
    const int slot = (m < 5) ? m : 6;
    const int i = blockIdx.x * 256 + threadIdx.x;
    out[(size_t)slot * 65536 + i] = (_Float16)src[m][i];
}

// ---------------- W2 = s_wq @ t_wd (fp32 accum), b2 = s_wq @ t_bd ----------------
__global__ __launch_bounds__(256) void make_w2(
    const float* __restrict__ s_wq, const float* __restrict__ t_wd,
    const float* __restrict__ t_bd, _Float16* __restrict__ W2,
    float* __restrict__ b2)
{
    const int e = blockIdx.x;
    const int d = threadIdx.x;
    float acc = 0.0f;
    for (int c = 0; c < 256; ++c)
        acc = fmaf(s_wq[e * 256 + c], t_wd[c * 256 + d], acc);
    W2[e * 256 + d] = (_Float16)acc;
    if (d == 0) {
        float bb = 0.0f;
        for (int c = 0; c < 256; ++c) bb = fmaf(s_wq[e * 256 + c], t_bd[c], bb);
        b2[e] = bb;
    }
}

// ---------------- fp32 -> fp16 streaming conversion (one tensor) ----------------
__global__ __launch_bounds__(256) void cvt_f32_f16(
    const float* __restrict__ s, _Float16* __restrict__ d)
{
    const size_t i = ((size_t)blockIdx.x * 256 + threadIdx.x) * 8;
    f32x4 a = *(const f32x4*)(s + i);
    f32x4 b = *(const f32x4*)(s + i + 4);
    half8 h;
#pragma unroll
    for (int j = 0; j < 4; ++j) { h[j] = (_Float16)a[j]; h[4 + j] = (_Float16)b[j]; }
    *(half8*)(d + i) = h;
}

// ---------------- GEMM: C[M,*] = A[M,256] @ W[*,256]^T (+bias) ----------------
// fp16 A/B, global_load_lds(16) staging, double-buffered LDS, 1 barrier +
// vmcnt(0) per K-step with next-tile prefetch overlapping MFMA (2-phase).
// 128x128 tile, BK=64, 4 waves (2x2), wave = 4x4 16x16x32 tiles.
// DUAL: grid covers 512 weight rows; y<2 -> C0 with LN->NL map; y>=2 -> C1 ident.
template <int ROWMAP, bool DUAL, bool ADD_BIAS, bool OUT_F32>
__global__ __launch_bounds__(256, 2) void gemm16(
    const _Float16* __restrict__ Ap, const _Float16* __restrict__ W,
    const float* __restrict__ bias, void* __restrict__ C0, void* __restrict__ C1)
{
    __shared__ __align__(16) _Float16 lds[32768];   // 2 bufs x (A 8192 + B 8192)

    const int tid  = threadIdx.x;
    const int lane = tid & 63;
    const int l15  = lane & 15;
    const int lhi  = lane >> 4;
    const int wid  = tid >> 6;
    const int gid  = blockIdx.x;
    const int y    = DUAL ? (gid & 3) : (gid & 1);
    const int x    = DUAL ? (gid >> 2) : (gid >> 1);
    const int m0   = x * 128;
    const int n0   = y * 128;
    const int wr   = (wid >> 1) * 64;
    const int wc   = (wid & 1) * 64;

    auto stage = [&](int buf, int kt) {
        const int k0 = kt * 64;
        _Float16* Ad = lds + buf * 8192;
        _Float16* Bd = lds + 16384 + buf * 8192;
#pragma unroll
        for (int i = 0; i < 4; ++i) {
            const int c = i * 256 + tid;       // chunk 0..1023, lane-contiguous
            const int r = c >> 3, c8 = (c & 7) * 8;
            gld16(Ap + (size_t)(m0 + r) * 256 + k0 + c8, Ad + c * 8);
            gld16(W  + (size_t)(n0 + r) * 256 + k0 + c8, Bd + c * 8);
        }
    };

    f32x4 acc[4][4] = {};
    stage(0, 0);
    int cur = 0;
    for (int kt = 0; kt < 4; ++kt) {
        asm volatile("s_waitcnt vmcnt(0)" ::: "memory");
        __syncthreads();
        if (kt < 3) stage(cur ^ 1, kt + 1);
        const _Float16* Ab = lds + cur * 8192;
        const _Float16* Bb = lds + 16384 + cur * 8192;
#pragma unroll
        for (int kk = 0; kk < 2; ++kk) {
            half8 af[4], bf[4];
#pragma unroll
            for (int mi = 0; mi < 4; ++mi)
                af[mi] = *(const half8*)(Ab + (wr + mi * 16 + l15) * 64 + kk * 32 + lhi * 8);
#pragma unroll
            for (int nj = 0; nj < 4; ++nj)
                bf[nj] = *(const half8*)(Bb + (wc + nj * 16 + l15) * 64 + kk * 32 + lhi * 8);
#pragma unroll
            for (int mi = 0; mi < 4; ++mi)
#pragma unroll
                for (int nj = 0; nj < 4; ++nj)
                    acc[mi][nj] = MFMA16(af[mi], bf[nj], acc[mi][nj]);
        }
        cur ^= 1;
    }

    // epilogue: D layout col = lane&15, row = (lane>>4)*4 + j
    const bool hi = DUAL && (y >= 2);
    void* Cp = hi ? C1 : C0;
    const int cadj = hi ? 256 : 0;
#pragma unroll
    for (int mi = 0; mi < 4; ++mi) {
#pragma unroll
        for (int nj = 0; nj < 4; ++nj) {
            const int col = n0 + wc + nj * 16 + l15 - cadj;
            const float bv = ADD_BIAS ? bias[col] : 0.0f;
#pragma unroll
            for (int j = 0; j < 4; ++j) {
                const int trow = m0 + wr + mi * 16 + lhi * 4 + j;
                int orow;
                if (DUAL)             orow = hi ? trow : map_ln_nl(trow);
                else if (ROWMAP == 1) orow = map_ln_nl(trow);
                else if (ROWMAP == 2) orow = map_nl_ln(trow);
                else                  orow = trow;
                const float val = acc[mi][nj][j] + bv;
                if (OUT_F32)
                    ((float*)Cp)[(size_t)orow * 256 + col] = val;
                else
                    ((_Float16*)Cp)[(size_t)orow * 256 + col] = (_Float16)val;
            }
        }
    }
}

// ---------------- temporal attention: per (b,n,h), seq = L = 128, NL layout ----------------
__global__ __launch_bounds__(256) void attn_temporal(
    const _Float16* __restrict__ Q, const _Float16* __restrict__ K,
    const _Float16* __restrict__ V, _Float16* __restrict__ O)
{
    __shared__ __align__(16) _Float16 Vt[32][136];   // V^T: [d][l]
    __shared__ __align__(16) _Float16 P[128][136];   // probabilities

    const int tid  = threadIdx.x;
    const int lane = tid & 63;
    const int l15  = lane & 15;
    const int lhi  = lane >> 4;
    const int wid  = tid >> 6;
    const int bidx = blockIdx.x;
    const int h = bidx & 7;
    const int n = (bidx >> 3) & 63;
    const int b = bidx >> 9;
    const size_t base = ((size_t)(b * 64 + n) * 128) * 256 + (size_t)h * 32;

    {
        const int l  = tid >> 1;
        const int dh = (tid & 1) * 16;
        const _Float16* srcp = V + base + (size_t)l * 256 + dh;
        half8 v0 = *(const half8*)(srcp);
        half8 v1 = *(const half8*)(srcp + 8);
#pragma unroll
        for (int j = 0; j < 8; ++j) {
            Vt[dh + j][l]     = v0[j];
            Vt[dh + 8 + j][l] = v1[j];
        }
    }
    __syncthreads();

    half8 qa[2];
#pragma unroll
    for (int mi = 0; mi < 2; ++mi)
        qa[mi] = *(const half8*)(Q + base +
                  (size_t)(wid * 32 + mi * 16 + l15) * 256 + lhi * 8);
    f32x4 s[2][8] = {};
#pragma unroll
    for (int nt = 0; nt < 8; ++nt) {
        half8 kb = *(const half8*)(K + base +
                    (size_t)(nt * 16 + l15) * 256 + lhi * 8);
#pragma unroll
        for (int mi = 0; mi < 2; ++mi)
            s[mi][nt] = MFMA16(qa[mi], kb, s[mi][nt]);
    }

    const float scale = 0.17677669529663687f;  // 1/sqrt(32)
#pragma unroll
    for (int mi = 0; mi < 2; ++mi) {
#pragma unroll
        for (int j = 0; j < 4; ++j) {
            float m = s[mi][0][j];
#pragma unroll
            for (int nt = 1; nt < 8; ++nt) m = fmaxf(m, s[mi][nt][j]);
            m = fmaxf(m, __shfl_xor(m, 1));
            m = fmaxf(m, __shfl_xor(m, 2));
            m = fmaxf(m, __shfl_xor(m, 4));
            m = fmaxf(m, __shfl_xor(m, 8));
            float sum = 0.0f;
#pragma unroll
            for (int nt = 0; nt < 8; ++nt) {
                const float p = __expf((s[mi][nt][j] - m) * scale);
                s[mi][nt][j] = p;
                sum += p;
            }
            sum += __shfl_xor(sum, 1);
            sum += __shfl_xor(sum, 2);
            sum += __shfl_xor(sum, 4);
            sum += __shfl_xor(sum, 8);
            const float inv = 1.0f / sum;
            const int prow = wid * 32 + mi * 16 + lhi * 4 + j;
#pragma unroll
            for (int nt = 0; nt < 8; ++nt)
                P[prow][nt * 16 + l15] = (_Float16)(s[mi][nt][j] * inv);
        }
    }
    __syncthreads();

    f32x4 o[2][2] = {};
#pragma unroll
    for (int ks = 0; ks < 4; ++ks) {
        half8 pa[2];
#pragma unroll
        for (int mi = 0; mi < 2; ++mi)
            pa[mi] = *(const half8*)(&P[wid * 32 + mi * 16 + l15][ks * 32 + lhi * 8]);
#pragma unroll
        for (int dt = 0; dt < 2; ++dt) {
            half8 vb = *(const half8*)(&Vt[dt * 16 + l15][ks * 32 + lhi * 8]);
#pragma unroll
            for (int mi = 0; mi < 2; ++mi)
                o[mi][dt] = MFMA16(pa[mi], vb, o[mi][dt]);
        }
    }
#pragma unroll
    for (int mi = 0; mi < 2; ++mi)
#pragma unroll
        for (int dt = 0; dt < 2; ++dt)
#pragma unroll
            for (int j = 0; j < 4; ++j)
                O[base + (size_t)(wid * 32 + mi * 16 + lhi * 4 + j) * 256 +
                  dt * 16 + l15] = (_Float16)o[mi][dt][j];
}

// ---------------- social attention: per (b,l,h), seq = N = 64, LN layout ----------------
__global__ __launch_bounds__(256) void attn_social(
    const _Float16* __restrict__ Q, const _Float16* __restrict__ K,
    const _Float16* __restrict__ V, _Float16* __restrict__ O)
{
    __shared__ __align__(16) _Float16 Vt[32][72];
    __shared__ __align__(16) _Float16 P[64][72];

    const int tid  = threadIdx.x;
    const int lane = tid & 63;
    const int l15  = lane & 15;
    const int lhi  = lane >> 4;
    const int wid  = tid >> 6;
    const int bidx = blockIdx.x;
    const int h = bidx & 7;
    const int l = (bidx >> 3) & 127;
    const int b = bidx >> 10;
    const size_t base = (((size_t)b * 128 + l) * 64) * 256 + (size_t)h * 32;

    {
        const int n  = tid >> 2;
        const int dq = (tid & 3) * 8;
        half8 v0 = *(const half8*)(V + base + (size_t)n * 256 + dq);
#pragma unroll
        for (int j = 0; j < 8; ++j) Vt[dq + j][n] = v0[j];
    }
    __syncthreads();

    half8 qa = *(const half8*)(Q + base + (size_t)(wid * 16 + l15) * 256 + lhi * 8);
    f32x4 s[4] = {};
#pragma unroll
    for (int nt = 0; nt < 4; ++nt) {
        half8 kb = *(const half8*)(K + base + (size_t)(nt * 16 + l15) * 256 + lhi * 8);
        s[nt] = MFMA16(qa, kb, s[nt]);
    }

    const float scale = 0.17677669529663687f;
#pragma unroll
    for (int j = 0; j < 4; ++j) {
        float m = s[0][j];
#pragma unroll
        for (int nt = 1; nt < 4; ++nt) m = fmaxf(m, s[nt][j]);
        m = fmaxf(m, __shfl_xor(m, 1));
        m = fmaxf(m, __shfl_xor(m, 2));
        m = fmaxf(m, __shfl_xor(m, 4));
        m = fmaxf(m, __shfl_xor(m, 8));
        float sum = 0.0f;
#pragma unroll
        for (int nt = 0; nt < 4; ++nt) {
            const float p = __expf((s[nt][j] - m) * scale);
            s[nt][j] = p;
            sum += p;
        }
        sum += __shfl_xor(sum, 1);
        sum += __shfl_xor(sum, 2);
        sum += __shfl_xor(sum, 4);
        sum += __shfl_xor(sum, 8);
        const float inv = 1.0f / sum;
        const int prow = wid * 16 + lhi * 4 + j;
#pragma unroll
        for (int nt = 0; nt < 4; ++nt)
            P[prow][nt * 16 + l15] = (_Float16)(s[nt][j] * inv);
    }
    __syncthreads();

    f32x4 o[2] = {};
#pragma unroll
    for (int ks = 0; ks < 2; ++ks) {
        half8 pa = *(const half8*)(&P[wid * 16 + l15][ks * 32 + lhi * 8]);
#pragma unroll
        for (int dt = 0; dt < 2; ++dt) {
            half8 vb = *(const half8*)(&Vt[dt * 16 + l15][ks * 32 + lhi * 8]);
            o[dt] = MFMA16(pa, vb, o[dt]);
        }
    }
#pragma unroll
    for (int dt = 0; dt < 2; ++dt)
#pragma unroll
        for (int j = 0; j < 4; ++j)
            O[base + (size_t)(wid * 16 + lhi * 4 + j) * 256 + dt * 16 + l15] =
                (_Float16)o[dt][j];
}

// ---------------- host launch ----------------
extern "C" void kernel_launch(void* const* d_in, const int* in_sizes, int n_in,
                              void* d_out, int out_size, void* d_ws, size_t ws_size,
                              hipStream_t stream)
{
    const float* q    = (const float*)d_in[0];
    const float* k    = (const float*)d_in[1];
    const float* v    = (const float*)d_in[2];
    const float* t_wq = (const float*)d_in[3];
    const float* t_wk = (const float*)d_in[4];
    const float* t_wv = (const float*)d_in[5];
    const float* t_wd = (const float*)d_in[6];
    const float* t_bd = (const float*)d_in[7];
    const float* s_wq = (const float*)d_in[8];
    const float* s_wk = (const float*)d_in[9];
    const float* s_wv = (const float*)d_in[10];
    const float* s_wd = (const float*)d_in[11];
    const float* s_bd = (const float*)d_in[12];

    // workspace: 7 fp16 weight slots + b2 (fp32) + 6 activation slots (32 MB)
    _Float16* Wb = (_Float16*)d_ws;
    float* b2 = (float*)(Wb + 7 * 65536);
    const size_t SLOT = (size_t)65536 * 256;
    _Float16* S0 = (_Float16*)(b2 + 256);
    _Float16* S1 = S0 + SLOT;
    _Float16* S2 = S0 + 2 * SLOT;
    _Float16* S3 = S0 + 3 * SLOT;
    _Float16* S4 = S0 + 4 * SLOT;
    _Float16* S5 = S0 + 5 * SLOT;

    cvt_weights<<<dim3(256, 6), 256, 0, stream>>>(
        t_wq, t_wk, s_wk, t_wv, s_wv, s_wd, Wb);
    make_w2<<<256, 256, 0, stream>>>(s_wq, t_wd, t_bd, Wb + 5 * 65536, b2);

    const dim3 gb(256);
    // q16 -> S0; Qt(NL) = q16 @ t_wq^T -> S1
    cvt_f32_f16<<<8192, gb, 0, stream>>>(q, S0);
    gemm16<1, false, false, false><<<1024, gb, 0, stream>>>(
        S0, Wb + 0 * 65536, nullptr, S1, nullptr);
    // k16 -> S0; Kt(NL) -> S2, Ks(LN) -> S3  (dual over [t_wk; s_wk])
    cvt_f32_f16<<<8192, gb, 0, stream>>>(k, S0);
    gemm16<1, true, false, false><<<2048, gb, 0, stream>>>(
        S0, Wb + 1 * 65536, nullptr, S2, S3);
    // v16 -> S0; Vt(NL) -> S4, Vs(LN) -> S5
    cvt_f32_f16<<<8192, gb, 0, stream>>>(v, S0);
    gemm16<1, true, false, false><<<2048, gb, 0, stream>>>(
        S0, Wb + 3 * 65536, nullptr, S4, S5);

    attn_temporal<<<4096, gb, 0, stream>>>(S1, S2, S4, S0);   // Ot(NL) -> S0

    // Qs(LN) = Ot @ W2^T + b2 -> S1
    gemm16<2, false, true, false><<<1024, gb, 0, stream>>>(
        S0, Wb + 5 * 65536, b2, S1, nullptr);

    attn_social<<<8192, gb, 0, stream>>>(S1, S3, S5, S2);     // Os(LN) -> S2

    gemm16<0, false, true, true><<<1024, gb, 0, stream>>>(
        S2, Wb + 6 * 65536, s_bd, d_out, nullptr);

    (void)in_sizes; (void)n_in; (void)out_size; (void)ws_size;
}

// Round 4
// 318.958 us; speedup vs baseline: 1.1264x; 1.0100x over previous
//
#include <hip/hip_runtime.h>

typedef __attribute__((ext_vector_type(8))) _Float16 half8;
typedef __attribute__((ext_vector_type(4))) _Float16 half4;
typedef __attribute__((ext_vector_type(4))) float f32x4;

#define MFMA16(a, b, c) __builtin_amdgcn_mfma_f32_16x16x32_f16((a), (b), (c), 0, 0, 0)

// B=8, L=128, N=64, D=256, H=8, dk=32.  M = 65536 tokens.
// Token orders: LN = (b,l,n), NL = (b,n,l).

__device__ inline int map_ln_nl(int t) {   // (b,l,n) -> (b,n,l)
    return (t & ~8191) | ((t & 63) << 7) | ((t >> 6) & 127);
}
__device__ inline int map_nl_ln(int t) {   // (b,n,l) -> (b,l,n)
    return (t & ~8191) | ((t & 127) << 6) | ((t >> 7) & 63);
}

typedef const __attribute__((address_space(1))) unsigned int guint;
typedef __attribute__((address_space(3))) unsigned int luint;
__device__ inline void gld16(const _Float16* g, _Float16* l) {
    __builtin_amdgcn_global_load_lds((guint*)g, (luint*)l, 16, 0, 0);
}

// ---------------- weight fp32 -> fp16 ----------------
// slots: 0=t_wq 1=t_wk 2=s_wk 3=t_wv 4=s_wv 5=W2(made elsewhere) 6=s_wd
__global__ __launch_bounds__(256) void cvt_weights(
    const float* __restrict__ w0, const float* __restrict__ w1,
    const float* __restrict__ w2, const float* __restrict__ w3,
    const float* __restrict__ w4, const float* __restrict__ w5,
    _Float16* __restrict__ out)
{
    const float* src[6] = {w0, w1, w2, w3, w4, w5};
    const int m = blockIdx.y;
    const int slot = (m < 5) ? m : 6;
    const int i = blockIdx.x * 256 + threadIdx.x;
    out[(size_t)slot * 65536 + i] = (_Float16)src[m][i];
}

// ---------------- W2 = s_wq @ t_wd (fp32 accum), b2 = s_wq @ t_bd ----------------
__global__ __launch_bounds__(256) void make_w2(
    const float* __restrict__ s_wq, const float* __restrict__ t_wd,
    const float* __restrict__ t_bd, _Float16* __restrict__ W2,
    float* __restrict__ b2)
{
    const int e = blockIdx.x;
    const int d = threadIdx.x;
    float acc = 0.0f;
    for (int c = 0; c < 256; ++c)
        acc = fmaf(s_wq[e * 256 + c], t_wd[c * 256 + d], acc);
    W2[e * 256 + d] = (_Float16)acc;
    if (d == 0) {
        float bb = 0.0f;
        for (int c = 0; c < 256; ++c) bb = fmaf(s_wq[e * 256 + c], t_bd[c], bb);
        b2[e] = bb;
    }
}

// ---------------- GEMM: C[M,*] = A[M,256] @ W[*,256]^T (+bias) ----------------
// 128x128 tile, BK=64, 4 waves (2x2), wave = 4x4 16x16x32 tiles.
// B staged via global_load_lds(16).  A: fp16 via global_load_lds(16), or fp32
// via reg-staged cvt (loads for tile t+1 issued before tile t's MFMA phase).
// Double-buffered LDS, one barrier + vmcnt(0) per K-step.
// DUAL: grid covers 512 weight rows; y<2 -> C0 with LN->NL map; y>=2 -> C1 ident.
template <bool A_F32, int ROWMAP, bool DUAL, bool ADD_BIAS, bool OUT_F32>
__global__ __launch_bounds__(256) void gemm16(
    const void* __restrict__ Ap, const _Float16* __restrict__ W,
    const float* __restrict__ bias, void* __restrict__ C0, void* __restrict__ C1)
{
    __shared__ __align__(16) _Float16 lds[32768];   // 2 bufs x (A 8192 + B 8192)

    const int tid  = threadIdx.x;
    const int lane = tid & 63;
    const int l15  = lane & 15;
    const int lhi  = lane >> 4;
    const int wid  = tid >> 6;
    const int gid  = blockIdx.x;
    const int y    = DUAL ? (gid & 3) : (gid & 1);
    const int x    = DUAL ? (gid >> 2) : (gid >> 1);
    const int m0   = x * 128;
    const int n0   = y * 128;
    const int wr   = (wid >> 1) * 64;
    const int wc   = (wid & 1) * 64;

    int rr[4], cc[4];
#pragma unroll
    for (int i = 0; i < 4; ++i) {
        const int c = i * 256 + tid;       // chunk 0..1023, lane-contiguous
        rr[i] = c >> 3;
        cc[i] = (c & 7) * 8;
    }

    f32x4 ar[4][2];   // fp32-A staging registers (32 floats/thread)

    auto issueA32 = [&](int kt) {
        const float* A = (const float*)Ap;
        const int k0 = kt * 64;
#pragma unroll
        for (int i = 0; i < 4; ++i) {
            const float* p = A + (size_t)(m0 + rr[i]) * 256 + k0 + cc[i];
            ar[i][0] = *(const f32x4*)(p);
            ar[i][1] = *(const f32x4*)(p + 4);
        }
    };
    auto writeA32 = [&](int buf) {
        _Float16* Ad = lds + buf * 8192;
#pragma unroll
        for (int i = 0; i < 4; ++i) {
            half8 h;
#pragma unroll
            for (int jj = 0; jj < 4; ++jj) {
                h[jj]     = (_Float16)ar[i][0][jj];
                h[4 + jj] = (_Float16)ar[i][1][jj];
            }
            *(half8*)(Ad + (i * 256 + tid) * 8) = h;
        }
    };
    auto stageA16 = [&](int buf, int kt) {
        const _Float16* A = (const _Float16*)Ap;
        _Float16* Ad = lds + buf * 8192;
        const int k0 = kt * 64;
#pragma unroll
        for (int i = 0; i < 4; ++i)
            gld16(A + (size_t)(m0 + rr[i]) * 256 + k0 + cc[i],
                  Ad + (i * 256 + tid) * 8);
    };
    auto stageB = [&](int buf, int kt) {
        _Float16* Bd = lds + 16384 + buf * 8192;
        const int k0 = kt * 64;
#pragma unroll
        for (int i = 0; i < 4; ++i)
            gld16(W + (size_t)(n0 + rr[i]) * 256 + k0 + cc[i],
                  Bd + (i * 256 + tid) * 8);
    };

    f32x4 acc[4][4] = {};
    if (A_F32) issueA32(0); else stageA16(0, 0);
    stageB(0, 0);
    int cur = 0;
    for (int kt = 0; kt < 4; ++kt) {
        asm volatile("s_waitcnt vmcnt(0)" ::: "memory");
        if (A_F32) writeA32(cur);
        __syncthreads();
        if (kt < 3) {
            if (A_F32) issueA32(kt + 1); else stageA16(cur ^ 1, kt + 1);
            stageB(cur ^ 1, kt + 1);
        }
        const _Float16* Ab = lds + cur * 8192;
        const _Float16* Bb = lds + 16384 + cur * 8192;
#pragma unroll
        for (int kk = 0; kk < 2; ++kk) {
            half8 af[4], bf[4];
#pragma unroll
            for (int mi = 0; mi < 4; ++mi)
                af[mi] = *(const half8*)(Ab + (wr + mi * 16 + l15) * 64 + kk * 32 + lhi * 8);
#pragma unroll
            for (int nj = 0; nj < 4; ++nj)
                bf[nj] = *(const half8*)(Bb + (wc + nj * 16 + l15) * 64 + kk * 32 + lhi * 8);
#pragma unroll
            for (int mi = 0; mi < 4; ++mi)
#pragma unroll
                for (int nj = 0; nj < 4; ++nj)
                    acc[mi][nj] = MFMA16(af[mi], bf[nj], acc[mi][nj]);
        }
        cur ^= 1;
    }

    // epilogue: D layout col = lane&15, row = (lane>>4)*4 + j
    const bool hi = DUAL && (y >= 2);
    void* Cp = hi ? C1 : C0;
    const int cadj = hi ? 256 : 0;
#pragma unroll
    for (int mi = 0; mi < 4; ++mi) {
#pragma unroll
        for (int nj = 0; nj < 4; ++nj) {
            const int col = n0 + wc + nj * 16 + l15 - cadj;
            const float bv = ADD_BIAS ? bias[col] : 0.0f;
#pragma unroll
            for (int j = 0; j < 4; ++j) {
                const int trow = m0 + wr + mi * 16 + lhi * 4 + j;
                int orow;
                if (DUAL)             orow = hi ? trow : map_ln_nl(trow);
                else if (ROWMAP == 1) orow = map_ln_nl(trow);
                else if (ROWMAP == 2) orow = map_nl_ln(trow);
                else                  orow = trow;
                const float val = acc[mi][nj][j] + bv;
                if (OUT_F32)
                    ((float*)Cp)[(size_t)orow * 256 + col] = val;
                else
                    ((_Float16*)Cp)[(size_t)orow * 256 + col] = (_Float16)val;
            }
        }
    }
}

// ---------------- temporal attention: per (b,n,h), seq = L = 128, NL layout ----------------
// Swapped QK^T: st = mfma(K_frag, Q_frag) -> lane holds S^T[k=rt*16+lhi*4+j][q=..+l15].
// Softmax reduce = in-lane + shfl_xor(16,32); P written as half4 (b64).
__global__ __launch_bounds__(256) void attn_temporal(
    const _Float16* __restrict__ Q, const _Float16* __restrict__ K,
    const _Float16* __restrict__ V, _Float16* __restrict__ O)
{
    __shared__ __align__(16) _Float16 Vt[32][136];   // V^T: [d][l]
    __shared__ __align__(16) _Float16 P[128][136];   // probabilities [q][k]

    const int tid  = threadIdx.x;
    const int lane = tid & 63;
    const int l15  = lane & 15;
    const int lhi  = lane >> 4;
    const int wid  = tid >> 6;
    const int bidx = blockIdx.x;
    const int h = bidx & 7;
    const int n = (bidx >> 3) & 63;
    const int b = bidx >> 9;
    const size_t base = ((size_t)(b * 64 + n) * 128) * 256 + (size_t)h * 32;

    // cooperative V transpose into LDS
    {
        const int l  = tid >> 1;
        const int dh = (tid & 1) * 16;
        const _Float16* srcp = V + base + (size_t)l * 256 + dh;
        half8 v0 = *(const half8*)(srcp);
        half8 v1 = *(const half8*)(srcp + 8);
#pragma unroll
        for (int j = 0; j < 8; ++j) {
            Vt[dh + j][l]     = v0[j];
            Vt[dh + 8 + j][l] = v1[j];
        }
    }
    __syncthreads();

    // S^T = K Q^T : wave owns q-cols [wid*32, wid*32+32), all 128 k-rows
    half8 qf[2];
#pragma unroll
    for (int ct = 0; ct < 2; ++ct)
        qf[ct] = *(const half8*)(Q + base +
                  (size_t)(wid * 32 + ct * 16 + l15) * 256 + lhi * 8);
    f32x4 st[2][8] = {};
#pragma unroll
    for (int rt = 0; rt < 8; ++rt) {
        half8 kf = *(const half8*)(K + base +
                    (size_t)(rt * 16 + l15) * 256 + lhi * 8);
#pragma unroll
        for (int ct = 0; ct < 2; ++ct)
            st[ct][rt] = MFMA16(kf, qf[ct], st[ct][rt]);
    }

    const float scale = 0.17677669529663687f;  // 1/sqrt(32)
#pragma unroll
    for (int ct = 0; ct < 2; ++ct) {
        const int q = wid * 32 + ct * 16 + l15;
        float m = st[ct][0][0];
#pragma unroll
        for (int rt = 0; rt < 8; ++rt)
#pragma unroll
            for (int j = 0; j < 4; ++j) m = fmaxf(m, st[ct][rt][j]);
        m = fmaxf(m, __shfl_xor(m, 16));
        m = fmaxf(m, __shfl_xor(m, 32));
        float sum = 0.0f;
#pragma unroll
        for (int rt = 0; rt < 8; ++rt)
#pragma unroll
            for (int j = 0; j < 4; ++j) {
                const float p = __expf((st[ct][rt][j] - m) * scale);
                st[ct][rt][j] = p;
                sum += p;
            }
        sum += __shfl_xor(sum, 16);
        sum += __shfl_xor(sum, 32);
        const float inv = 1.0f / sum;
#pragma unroll
        for (int rt = 0; rt < 8; ++rt) {
            half4 hv;
#pragma unroll
            for (int j = 0; j < 4; ++j) hv[j] = (_Float16)(st[ct][rt][j] * inv);
            *(half4*)(&P[q][rt * 16 + lhi * 4]) = hv;
        }
    }
    __syncthreads();

    // O = P V
    f32x4 o[2][2] = {};
#pragma unroll
    for (int ks = 0; ks < 4; ++ks) {
        half8 pa[2];
#pragma unroll
        for (int mi = 0; mi < 2; ++mi)
            pa[mi] = *(const half8*)(&P[wid * 32 + mi * 16 + l15][ks * 32 + lhi * 8]);
#pragma unroll
        for (int dt = 0; dt < 2; ++dt) {
            half8 vb = *(const half8*)(&Vt[dt * 16 + l15][ks * 32 + lhi * 8]);
#pragma unroll
            for (int mi = 0; mi < 2; ++mi)
                o[mi][dt] = MFMA16(pa[mi], vb, o[mi][dt]);
        }
    }
#pragma unroll
    for (int mi = 0; mi < 2; ++mi)
#pragma unroll
        for (int dt = 0; dt < 2; ++dt)
#pragma unroll
            for (int j = 0; j < 4; ++j)
                O[base + (size_t)(wid * 32 + mi * 16 + lhi * 4 + j) * 256 +
                  dt * 16 + l15] = (_Float16)o[mi][dt][j];
}

// ---------------- social attention: per (b,l,h), seq = N = 64, LN layout ----------------
__global__ __launch_bounds__(256) void attn_social(
    const _Float16* __restrict__ Q, const _Float16* __restrict__ K,
    const _Float16* __restrict__ V, _Float16* __restrict__ O)
{
    __shared__ __align__(16) _Float16 Vt[32][72];
    __shared__ __align__(16) _Float16 P[64][72];

    const int tid  = threadIdx.x;
    const int lane = tid & 63;
    const int l15  = lane & 15;
    const int lhi  = lane >> 4;
    const int wid  = tid >> 6;
    const int bidx = blockIdx.x;
    const int h = bidx & 7;
    const int l = (bidx >> 3) & 127;
    const int b = bidx >> 10;
    const size_t base = (((size_t)b * 128 + l) * 64) * 256 + (size_t)h * 32;

    {
        const int n  = tid >> 2;
        const int dq = (tid & 3) * 8;
        half8 v0 = *(const half8*)(V + base + (size_t)n * 256 + dq);
#pragma unroll
        for (int j = 0; j < 8; ++j) Vt[dq + j][n] = v0[j];
    }
    __syncthreads();

    // S^T : wave owns q-cols [wid*16, wid*16+16), all 64 k-rows
    half8 qf = *(const half8*)(Q + base + (size_t)(wid * 16 + l15) * 256 + lhi * 8);
    f32x4 st[4] = {};
#pragma unroll
    for (int rt = 0; rt < 4; ++rt) {
        half8 kf = *(const half8*)(K + base + (size_t)(rt * 16 + l15) * 256 + lhi * 8);
        st[rt] = MFMA16(kf, qf, st[rt]);
    }

    const float scale = 0.17677669529663687f;
    {
        const int q = wid * 16 + l15;
        float m = st[0][0];
#pragma unroll
        for (int rt = 0; rt < 4; ++rt)
#pragma unroll
            for (int j = 0; j < 4; ++j) m = fmaxf(m, st[rt][j]);
        m = fmaxf(m, __shfl_xor(m, 16));
        m = fmaxf(m, __shfl_xor(m, 32));
        float sum = 0.0f;
#pragma unroll
        for (int rt = 0; rt < 4; ++rt)
#pragma unroll
            for (int j = 0; j < 4; ++j) {
                const float p = __expf((st[rt][j] - m) * scale);
                st[rt][j] = p;
                sum += p;
            }
        sum += __shfl_xor(sum, 16);
        sum += __shfl_xor(sum, 32);
        const float inv = 1.0f / sum;
#pragma unroll
        for (int rt = 0; rt < 4; ++rt) {
            half4 hv;
#pragma unroll
            for (int j = 0; j < 4; ++j) hv[j] = (_Float16)(st[rt][j] * inv);
            *(half4*)(&P[q][rt * 16 + lhi * 4]) = hv;
        }
    }
    __syncthreads();

    f32x4 o[2] = {};
#pragma unroll
    for (int ks = 0; ks < 2; ++ks) {
        half8 pa = *(const half8*)(&P[wid * 16 + l15][ks * 32 + lhi * 8]);
#pragma unroll
        for (int dt = 0; dt < 2; ++dt) {
            half8 vb = *(const half8*)(&Vt[dt * 16 + l15][ks * 32 + lhi * 8]);
            o[dt] = MFMA16(pa, vb, o[dt]);
        }
    }
#pragma unroll
    for (int dt = 0; dt < 2; ++dt)
#pragma unroll
        for (int j = 0; j < 4; ++j)
            O[base + (size_t)(wid * 16 + lhi * 4 + j) * 256 + dt * 16 + l15] =
                (_Float16)o[dt][j];
}

// ---------------- host launch ----------------
extern "C" void kernel_launch(void* const* d_in, const int* in_sizes, int n_in,
                              void* d_out, int out_size, void* d_ws, size_t ws_size,
                              hipStream_t stream)
{
    const float* q    = (const float*)d_in[0];
    const float* k    = (const float*)d_in[1];
    const float* v    = (const float*)d_in[2];
    const float* t_wq = (const float*)d_in[3];
    const float* t_wk = (const float*)d_in[4];
    const float* t_wv = (const float*)d_in[5];
    const float* t_wd = (const float*)d_in[6];
    const float* t_bd = (const float*)d_in[7];
    const float* s_wq = (const float*)d_in[8];
    const float* s_wk = (const float*)d_in[9];
    const float* s_wv = (const float*)d_in[10];
    const float* s_wd = (const float*)d_in[11];
    const float* s_bd = (const float*)d_in[12];

    // workspace: 7 fp16 weight slots + b2 (fp32) + 6 activation slots (32 MB)
    _Float16* Wb = (_Float16*)d_ws;
    float* b2 = (float*)(Wb + 7 * 65536);
    const size_t SLOT = (size_t)65536 * 256;
    _Float16* S0 = (_Float16*)(b2 + 256);
    _Float16* S1 = S0 + SLOT;
    _Float16* S2 = S0 + 2 * SLOT;
    _Float16* S3 = S0 + 3 * SLOT;
    _Float16* S4 = S0 + 4 * SLOT;
    _Float16* S5 = S0 + 5 * SLOT;

    cvt_weights<<<dim3(256, 6), 256, 0, stream>>>(
        t_wq, t_wk, s_wk, t_wv, s_wv, s_wd, Wb);
    make_w2<<<256, 256, 0, stream>>>(s_wq, t_wd, t_bd, Wb + 5 * 65536, b2);

    const dim3 gb(256);
    // Qt(NL) = q @ t_wq^T -> S1   (fp32 A read directly)
    gemm16<true, 1, false, false, false><<<1024, gb, 0, stream>>>(
        q, Wb + 0 * 65536, nullptr, S1, nullptr);
    // Kt(NL) -> S2, Ks(LN) -> S3  (dual over [t_wk; s_wk])
    gemm16<true, 1, true, false, false><<<2048, gb, 0, stream>>>(
        k, Wb + 1 * 65536, nullptr, S2, S3);
    // Vt(NL) -> S4, Vs(LN) -> S5
    gemm16<true, 1, true, false, false><<<2048, gb, 0, stream>>>(
        v, Wb + 3 * 65536, nullptr, S4, S5);

    attn_temporal<<<4096, gb, 0, stream>>>(S1, S2, S4, S0);   // Ot(NL) -> S0

    // Qs(LN) = Ot @ W2^T + b2 -> S1
    gemm16<false, 2, false, true, false><<<1024, gb, 0, stream>>>(
        S0, Wb + 5 * 65536, b2, S1, nullptr);

    attn_social<<<8192, gb, 0, stream>>>(S1, S3, S5, S2);     // Os(LN) -> S2

    gemm16<false, 0, false, true, true><<<1024, gb, 0, stream>>>(
        S2, Wb + 6 * 65536, s_bd, d_out, nullptr);

    (void)in_sizes; (void)n_in; (void)out_size; (void)ws_size;
}

// Round 5
// 299.078 us; speedup vs baseline: 1.2012x; 1.0665x over previous
//
#include <hip/hip_runtime.h>

typedef __attribute__((ext_vector_type(8))) _Float16 half8;
typedef __attribute__((ext_vector_type(4))) _Float16 half4;
typedef __attribute__((ext_vector_type(4))) float f32x4;

#define MFMA16(a, b, c) __builtin_amdgcn_mfma_f32_16x16x32_f16((a), (b), (c), 0, 0, 0)

// B=8, L=128, N=64, D=256, H=8, dk=32.  M = 65536 tokens.
// Token orders: LN = (b,l,n), NL = (b,n,l).

__device__ inline int map_ln_nl(int t) {   // (b,l,n) -> (b,n,l)
    return (t & ~8191) | ((t & 63) << 7) | ((t >> 6) & 127);
}
__device__ inline int map_nl_ln(int t) {   // (b,n,l) -> (b,l,n)
    return (t & ~8191) | ((t & 127) << 6) | ((t >> 7) & 63);
}

typedef const __attribute__((address_space(1))) unsigned int guint;
typedef __attribute__((address_space(3))) unsigned int luint;
__device__ inline void gld16(const _Float16* g, _Float16* l) {
    __builtin_amdgcn_global_load_lds((guint*)g, (luint*)l, 16, 0, 0);
}

// ---------------- weight fp32 -> fp16 ----------------
// slots: 0=t_wq 1=t_wk 2=s_wk 3=t_wv 4=s_wv 5=W2(made elsewhere) 6=s_wd
__global__ __launch_bounds__(256) void cvt_weights(
    const float* __restrict__ w0, const float* __restrict__ w1,
    const float* __restrict__ w2, const float* __restrict__ w3,
    const float* __restrict__ w4, const float* __restrict__ w5,
    _Float16* __restrict__ out)
{
    const float* src[6] = {w0, w1, w2, w3, w4, w5};
    const int m = blockIdx.y;
    const int slot = (m < 5) ? m : 6;
    const int i = blockIdx.x * 256 + threadIdx.x;
    out[(size_t)slot * 65536 + i] = (_Float16)src[m][i];
}

// ---------------- W2 = s_wq @ t_wd (fp32 accum), b2 = s_wq @ t_bd ----------------
__global__ __launch_bounds__(256) void make_w2(
    const float* __restrict__ s_wq, const float* __restrict__ t_wd,
    const float* __restrict__ t_bd, _Float16* __restrict__ W2,
    float* __restrict__ b2)
{
    const int e = blockIdx.x;
    const int d = threadIdx.x;
    float acc = 0.0f;
    for (int c = 0; c < 256; ++c)
        acc = fmaf(s_wq[e * 256 + c], t_wd[c * 256 + d], acc);
    W2[e * 256 + d] = (_Float16)acc;
    if (d == 0) {
        float bb = 0.0f;
        for (int c = 0; c < 256; ++c) bb = fmaf(s_wq[e * 256 + c], t_bd[c], bb);
        b2[e] = bb;
    }
}

// ---------------- GEMM: C[M,*] = A[M,256] @ W[*,256]^T (+bias) ----------------
// 128x128 tile, BK=64, 4 waves (2x2), wave = 4x4 16x16x32 tiles.
// LDS layout is XOR-swizzled via PRE-SWIZZLED GLOBAL SOURCE (rule #21):
// physical chunk p=(r,jp) holds logical (r, jp^(r&7)); ds_read applies the
// same XOR.  16-lane read groups then alias banks only 2-way (free, m136).
// Bijective XCD swizzle (m204): col-blocks sharing an A-panel land on the
// same XCD back-to-back -> A fetched once into that XCD's L2.
// DUAL: grid covers 512 weight rows; y<2 -> C0 with LN->NL map; y>=2 -> C1.
template <bool A_F32, int ROWMAP, bool DUAL, bool ADD_BIAS, bool OUT_F32>
__global__ __launch_bounds__(256) void gemm16(
    const void* __restrict__ Ap, const _Float16* __restrict__ W,
    const float* __restrict__ bias, void* __restrict__ C0, void* __restrict__ C1)
{
    __shared__ __align__(16) _Float16 lds[32768];   // 2 bufs x (A 8192 + B 8192)

    const int tid  = threadIdx.x;
    const int lane = tid & 63;
    const int l15  = lane & 15;
    const int lhi  = lane >> 4;
    const int wid  = tid >> 6;
    const int nwg  = gridDim.x;
    const int wg   = (blockIdx.x & 7) * (nwg >> 3) + (blockIdx.x >> 3);
    const int y    = DUAL ? (wg & 3) : (wg & 1);
    const int x    = DUAL ? (wg >> 2) : (wg >> 1);
    const int m0   = x * 128;
    const int n0   = y * 128;
    const int wr   = (wid >> 1) * 64;
    const int wc   = (wid & 1) * 64;

    int rr[4], cc[4];
#pragma unroll
    for (int i = 0; i < 4; ++i) {
        const int c = i * 256 + tid;       // physical chunk 0..1023
        const int r = c >> 3;
        rr[i] = r;
        cc[i] = (((c & 7) ^ (r & 7)) * 8); // pre-swizzled global column
    }

    f32x4 ar[4][2];   // fp32-A staging registers (32 floats/thread)

    auto issueA32 = [&](int kt) {
        const float* A = (const float*)Ap;
        const int k0 = kt * 64;
#pragma unroll
        for (int i = 0; i < 4; ++i) {
            const float* p = A + (size_t)(m0 + rr[i]) * 256 + k0 + cc[i];
            ar[i][0] = *(const f32x4*)(p);
            ar[i][1] = *(const f32x4*)(p + 4);
        }
    };
    auto writeA32 = [&](int buf) {
        _Float16* Ad = lds + buf * 8192;
#pragma unroll
        for (int i = 0; i < 4; ++i) {
            half8 h;
#pragma unroll
            for (int jj = 0; jj < 4; ++jj) {
                h[jj]     = (_Float16)ar[i][0][jj];
                h[4 + jj] = (_Float16)ar[i][1][jj];
            }
            *(half8*)(Ad + (i * 256 + tid) * 8) = h;
        }
    };
    auto stageA16 = [&](int buf, int kt) {
        const _Float16* A = (const _Float16*)Ap;
        _Float16* Ad = lds + buf * 8192;
        const int k0 = kt * 64;
#pragma unroll
        for (int i = 0; i < 4; ++i)
            gld16(A + (size_t)(m0 + rr[i]) * 256 + k0 + cc[i],
                  Ad + (i * 256 + tid) * 8);
    };
    auto stageB = [&](int buf, int kt) {
        _Float16* Bd = lds + 16384 + buf * 8192;
        const int k0 = kt * 64;
#pragma unroll
        for (int i = 0; i < 4; ++i)
            gld16(W + (size_t)(n0 + rr[i]) * 256 + k0 + cc[i],
                  Bd + (i * 256 + tid) * 8);
    };

    f32x4 acc[4][4] = {};
    if (A_F32) issueA32(0); else stageA16(0, 0);
    stageB(0, 0);
    int cur = 0;
    const int sw = l15 & 7;    // row&7 of every fragment row this lane reads
    for (int kt = 0; kt < 4; ++kt) {
        asm volatile("s_waitcnt vmcnt(0)" ::: "memory");
        if (A_F32) writeA32(cur);
        __syncthreads();
        if (kt < 3) {
            if (A_F32) issueA32(kt + 1); else stageA16(cur ^ 1, kt + 1);
            stageB(cur ^ 1, kt + 1);
        }
        const _Float16* Ab = lds + cur * 8192;
        const _Float16* Bb = lds + 16384 + cur * 8192;
#pragma unroll
        for (int kk = 0; kk < 2; ++kk) {
            const int co = ((kk * 4 + lhi) ^ sw) * 8;   // swizzled chunk offset
            half8 af[4], bf[4];
#pragma unroll
            for (int mi = 0; mi < 4; ++mi)
                af[mi] = *(const half8*)(Ab + (wr + mi * 16 + l15) * 64 + co);
#pragma unroll
            for (int nj = 0; nj < 4; ++nj)
                bf[nj] = *(const half8*)(Bb + (wc + nj * 16 + l15) * 64 + co);
#pragma unroll
            for (int mi = 0; mi < 4; ++mi)
#pragma unroll
                for (int nj = 0; nj < 4; ++nj)
                    acc[mi][nj] = MFMA16(af[mi], bf[nj], acc[mi][nj]);
        }
        cur ^= 1;
    }

    // epilogue: D layout col = lane&15, row = (lane>>4)*4 + j
    const bool hi = DUAL && (y >= 2);
    void* Cp = hi ? C1 : C0;
    const int cadj = hi ? 256 : 0;
#pragma unroll
    for (int mi = 0; mi < 4; ++mi) {
#pragma unroll
        for (int nj = 0; nj < 4; ++nj) {
            const int col = n0 + wc + nj * 16 + l15 - cadj;
            const float bv = ADD_BIAS ? bias[col] : 0.0f;
#pragma unroll
            for (int j = 0; j < 4; ++j) {
                const int trow = m0 + wr + mi * 16 + lhi * 4 + j;
                int orow;
                if (DUAL)             orow = hi ? trow : map_ln_nl(trow);
                else if (ROWMAP == 1) orow = map_ln_nl(trow);
                else if (ROWMAP == 2) orow = map_nl_ln(trow);
                else                  orow = trow;
                const float val = acc[mi][nj][j] + bv;
                if (OUT_F32)
                    ((float*)Cp)[(size_t)orow * 256 + col] = val;
                else
                    ((_Float16*)Cp)[(size_t)orow * 256 + col] = (_Float16)val;
            }
        }
    }
}

// ---------------- temporal attention: per (b,n,h), seq = L = 128, NL layout ----------------
// Swapped QK^T: st = mfma(K_frag, Q_frag) -> lane holds S^T[k=rt*16+lhi*4+j][q=..+l15].
// Softmax reduce = in-lane + shfl_xor(16,32); P written as half4 (b64).
__global__ __launch_bounds__(256) void attn_temporal(
    const _Float16* __restrict__ Q, const _Float16* __restrict__ K,
    const _Float16* __restrict__ V, _Float16* __restrict__ O)
{
    __shared__ __align__(16) _Float16 Vt[32][136];   // V^T: [d][l]
    __shared__ __align__(16) _Float16 P[128][136];   // probabilities [q][k]

    const int tid  = threadIdx.x;
    const int lane = tid & 63;
    const int l15  = lane & 15;
    const int lhi  = lane >> 4;
    const int wid  = tid >> 6;
    const int bidx = blockIdx.x;
    const int h = bidx & 7;
    const int n = (bidx >> 3) & 63;
    const int b = bidx >> 9;
    const size_t base = ((size_t)(b * 64 + n) * 128) * 256 + (size_t)h * 32;

    // cooperative V transpose into LDS
    {
        const int l  = tid >> 1;
        const int dh = (tid & 1) * 16;
        const _Float16* srcp = V + base + (size_t)l * 256 + dh;
        half8 v0 = *(const half8*)(srcp);
        half8 v1 = *(const half8*)(srcp + 8);
#pragma unroll
        for (int j = 0; j < 8; ++j) {
            Vt[dh + j][l]     = v0[j];
            Vt[dh + 8 + j][l] = v1[j];
        }
    }
    __syncthreads();

    // S^T = K Q^T : wave owns q-cols [wid*32, wid*32+32), all 128 k-rows
    half8 qf[2];
#pragma unroll
    for (int ct = 0; ct < 2; ++ct)
        qf[ct] = *(const half8*)(Q + base +
                  (size_t)(wid * 32 + ct * 16 + l15) * 256 + lhi * 8);
    f32x4 st[2][8] = {};
#pragma unroll
    for (int rt = 0; rt < 8; ++rt) {
        half8 kf = *(const half8*)(K + base +
                    (size_t)(rt * 16 + l15) * 256 + lhi * 8);
#pragma unroll
        for (int ct = 0; ct < 2; ++ct)
            st[ct][rt] = MFMA16(kf, qf[ct], st[ct][rt]);
    }

    const float scale = 0.17677669529663687f;  // 1/sqrt(32)
#pragma unroll
    for (int ct = 0; ct < 2; ++ct) {
        const int q = wid * 32 + ct * 16 + l15;
        float m = st[ct][0][0];
#pragma unroll
        for (int rt = 0; rt < 8; ++rt)
#pragma unroll
            for (int j = 0; j < 4; ++j) m = fmaxf(m, st[ct][rt][j]);
        m = fmaxf(m, __shfl_xor(m, 16));
        m = fmaxf(m, __shfl_xor(m, 32));
        float sum = 0.0f;
#pragma unroll
        for (int rt = 0; rt < 8; ++rt)
#pragma unroll
            for (int j = 0; j < 4; ++j) {
                const float p = __expf((st[ct][rt][j] - m) * scale);
                st[ct][rt][j] = p;
                sum += p;
            }
        sum += __shfl_xor(sum, 16);
        sum += __shfl_xor(sum, 32);
        const float inv = 1.0f / sum;
#pragma unroll
        for (int rt = 0; rt < 8; ++rt) {
            half4 hv;
#pragma unroll
            for (int j = 0; j < 4; ++j) hv[j] = (_Float16)(st[ct][rt][j] * inv);
            *(half4*)(&P[q][rt * 16 + lhi * 4]) = hv;
        }
    }
    __syncthreads();

    // O = P V
    f32x4 o[2][2] = {};
#pragma unroll
    for (int ks = 0; ks < 4; ++ks) {
        half8 pa[2];
#pragma unroll
        for (int mi = 0; mi < 2; ++mi)
            pa[mi] = *(const half8*)(&P[wid * 32 + mi * 16 + l15][ks * 32 + lhi * 8]);
#pragma unroll
        for (int dt = 0; dt < 2; ++dt) {
            half8 vb = *(const half8*)(&Vt[dt * 16 + l15][ks * 32 + lhi * 8]);
#pragma unroll
            for (int mi = 0; mi < 2; ++mi)
                o[mi][dt] = MFMA16(pa[mi], vb, o[mi][dt]);
        }
    }
#pragma unroll
    for (int mi = 0; mi < 2; ++mi)
#pragma unroll
        for (int dt = 0; dt < 2; ++dt)
#pragma unroll
            for (int j = 0; j < 4; ++j)
                O[base + (size_t)(wid * 32 + mi * 16 + lhi * 4 + j) * 256 +
                  dt * 16 + l15] = (_Float16)o[mi][dt][j];
}

// ---------------- social attention: per (b,l,h), seq = N = 64, LN layout ----------------
__global__ __launch_bounds__(256) void attn_social(
    const _Float16* __restrict__ Q, const _Float16* __restrict__ K,
    const _Float16* __restrict__ V, _Float16* __restrict__ O)
{
    __shared__ __align__(16) _Float16 Vt[32][72];
    __shared__ __align__(16) _Float16 P[64][72];

    const int tid  = threadIdx.x;
    const int lane = tid & 63;
    const int l15  = lane & 15;
    const int lhi  = lane >> 4;
    const int wid  = tid >> 6;
    const int bidx = blockIdx.x;
    const int h = bidx & 7;
    const int l = (bidx >> 3) & 127;
    const int b = bidx >> 10;
    const size_t base = (((size_t)b * 128 + l) * 64) * 256 + (size_t)h * 32;

    {
        const int n  = tid >> 2;
        const int dq = (tid & 3) * 8;
        half8 v0 = *(const half8*)(V + base + (size_t)n * 256 + dq);
#pragma unroll
        for (int j = 0; j < 8; ++j) Vt[dq + j][n] = v0[j];
    }
    __syncthreads();

    // S^T : wave owns q-cols [wid*16, wid*16+16), all 64 k-rows
    half8 qf = *(const half8*)(Q + base + (size_t)(wid * 16 + l15) * 256 + lhi * 8);
    f32x4 st[4] = {};
#pragma unroll
    for (int rt = 0; rt < 4; ++rt) {
        half8 kf = *(const half8*)(K + base + (size_t)(rt * 16 + l15) * 256 + lhi * 8);
        st[rt] = MFMA16(kf, qf, st[rt]);
    }

    const float scale = 0.17677669529663687f;
    {
        const int q = wid * 16 + l15;
        float m = st[0][0];
#pragma unroll
        for (int rt = 0; rt < 4; ++rt)
#pragma unroll
            for (int j = 0; j < 4; ++j) m = fmaxf(m, st[rt][j]);
        m = fmaxf(m, __shfl_xor(m, 16));
        m = fmaxf(m, __shfl_xor(m, 32));
        float sum = 0.0f;
#pragma unroll
        for (int rt = 0; rt < 4; ++rt)
#pragma unroll
            for (int j = 0; j < 4; ++j) {
                const float p = __expf((st[rt][j] - m) * scale);
                st[rt][j] = p;
                sum += p;
            }
        sum += __shfl_xor(sum, 16);
        sum += __shfl_xor(sum, 32);
        const float inv = 1.0f / sum;
#pragma unroll
        for (int rt = 0; rt < 4; ++rt) {
            half4 hv;
#pragma unroll
            for (int j = 0; j < 4; ++j) hv[j] = (_Float16)(st[rt][j] * inv);
            *(half4*)(&P[q][rt * 16 + lhi * 4]) = hv;
        }
    }
    __syncthreads();

    f32x4 o[2] = {};
#pragma unroll
    for (int ks = 0; ks < 2; ++ks) {
        half8 pa = *(const half8*)(&P[wid * 16 + l15][ks * 32 + lhi * 8]);
#pragma unroll
        for (int dt = 0; dt < 2; ++dt) {
            half8 vb = *(const half8*)(&Vt[dt * 16 + l15][ks * 32 + lhi * 8]);
            o[dt] = MFMA16(pa, vb, o[dt]);
        }
    }
#pragma unroll
    for (int dt = 0; dt < 2; ++dt)
#pragma unroll
        for (int j = 0; j < 4; ++j)
            O[base + (size_t)(wid * 16 + lhi * 4 + j) * 256 + dt * 16 + l15] =
                (_Float16)o[dt][j];
}

// ---------------- host launch ----------------
extern "C" void kernel_launch(void* const* d_in, const int* in_sizes, int n_in,
                              void* d_out, int out_size, void* d_ws, size_t ws_size,
                              hipStream_t stream)
{
    const float* q    = (const float*)d_in[0];
    const float* k    = (const float*)d_in[1];
    const float* v    = (const float*)d_in[2];
    const float* t_wq = (const float*)d_in[3];
    const float* t_wk = (const float*)d_in[4];
    const float* t_wv = (const float*)d_in[5];
    const float* t_wd = (const float*)d_in[6];
    const float* t_bd = (const float*)d_in[7];
    const float* s_wq = (const float*)d_in[8];
    const float* s_wk = (const float*)d_in[9];
    const float* s_wv = (const float*)d_in[10];
    const float* s_wd = (const float*)d_in[11];
    const float* s_bd = (const float*)d_in[12];

    // workspace: 7 fp16 weight slots + b2 (fp32) + 6 activation slots (32 MB)
    _Float16* Wb = (_Float16*)d_ws;
    float* b2 = (float*)(Wb + 7 * 65536);
    const size_t SLOT = (size_t)65536 * 256;
    _Float16* S0 = (_Float16*)(b2 + 256);
    _Float16* S1 = S0 + SLOT;
    _Float16* S2 = S0 + 2 * SLOT;
    _Float16* S3 = S0 + 3 * SLOT;
    _Float16* S4 = S0 + 4 * SLOT;
    _Float16* S5 = S0 + 5 * SLOT;

    cvt_weights<<<dim3(256, 6), 256, 0, stream>>>(
        t_wq, t_wk, s_wk, t_wv, s_wv, s_wd, Wb);
    make_w2<<<256, 256, 0, stream>>>(s_wq, t_wd, t_bd, Wb + 5 * 65536, b2);

    const dim3 gb(256);
    // Qt(NL) = q @ t_wq^T -> S1   (fp32 A read directly)
    gemm16<true, 1, false, false, false><<<1024, gb, 0, stream>>>(
        q, Wb + 0 * 65536, nullptr, S1, nullptr);
    // Kt(NL) -> S2, Ks(LN) -> S3  (dual over [t_wk; s_wk])
    gemm16<true, 1, true, false, false><<<2048, gb, 0, stream>>>(
        k, Wb + 1 * 65536, nullptr, S2, S3);
    // Vt(NL) -> S4, Vs(LN) -> S5
    gemm16<true, 1, true, false, false><<<2048, gb, 0, stream>>>(
        v, Wb + 3 * 65536, nullptr, S4, S5);

    attn_temporal<<<4096, gb, 0, stream>>>(S1, S2, S4, S0);   // Ot(NL) -> S0

    // Qs(LN) = Ot @ W2^T + b2 -> S1
    gemm16<false, 2, false, true, false><<<1024, gb, 0, stream>>>(
        S0, Wb + 5 * 65536, b2, S1, nullptr);

    attn_social<<<8192, gb, 0, stream>>>(S1, S3, S5, S2);     // Os(LN) -> S2

    gemm16<false, 0, false, true, true><<<1024, gb, 0, stream>>>(
        S2, Wb + 6 * 65536, s_bd, d_out, nullptr);

    (void)in_sizes; (void)n_in; (void)out_size; (void)ws_size;
}